// Round 3
// baseline (270.273 us; speedup 1.0000x reference)
//
#include <hip/hip_runtime.h>

// Dense 2D spatial transformer (bilinear warp, dense flow), 4096x4096 f32.
//
// Round 3: LDS-staged gather. Flow is ~N(0,1) so samples stay within ~6 px of
// identity. Each block computes a 16(rows) x 64(cols) output tile and stages
// the 32x80 image neighborhood (margin 8) into LDS via coalesced float4 loads;
// the 4 bilinear taps become LDS reads (random +-7 jitter -> mild bank
// conflicts only). Out-of-image stage slots hold 0.0 so the zero-pad border
// semantics need no predication on the LDS path. A per-lane global-gather
// fallback keeps correctness for |flow| beyond the margin (never taken for
// this input, but required for exactness).
//
// Reference math replicated bit-exactly (same as passing R1/R2 kernels):
//   H_up=(flow_h+h)+1 ; W_up=(flow_w+w)+1 ; hf=floor, hc=hf+1, clamp to
//   [0,H+1]; dH=(float)hc_clamped-H_up (clamp BEFORE weights); bilerp.

#define IMG_H 4096
#define IMG_W 4096
#define TILE_W 64
#define TILE_H 16
#define MARGIN 8
#define SROWS (TILE_H + 2*MARGIN)   // 32
#define SCOLS (TILE_W + 2*MARGIN)   // 80
#define SSTRIDE 84                  // 84*4=336 B row pitch: 16B-aligned rows, non-pow2 bank shift

__global__ __launch_bounds__(256) void warp_bilinear_kernel(
    const float* __restrict__ img,   // [H, W]
    const float* __restrict__ flow,  // [2, H, W]
    float* __restrict__ out)         // [H, W]
{
    __shared__ float tile[SROWS * SSTRIDE];

    const int tid  = threadIdx.x;
    const int h0   = blockIdx.y * TILE_H;
    const int w0   = blockIdx.x * TILE_W;
    const int row0 = h0 - MARGIN;
    const int col0 = w0 - MARGIN;
    const int HW   = IMG_H * IMG_W;

    const bool interior = (row0 >= 0) && (row0 + SROWS <= IMG_H) &&
                          (col0 >= 0) && (col0 + SCOLS <= IMG_W);

    if (interior) {
        // 32 rows x 20 float4 = 640 tasks; img row base is 16B-aligned
        // (col0*4 = bx*256 - 32, multiple of 16).
        #pragma unroll
        for (int base = 0; base < 3; ++base) {
            int t = base * 256 + tid;
            if (t < SROWS * 20) {
                int r = t / 20, c4 = t % 20;
                const float4 v = *reinterpret_cast<const float4*>(
                    img + (long)(row0 + r) * IMG_W + col0 + c4 * 4);
                *reinterpret_cast<float4*>(&tile[r * SSTRIDE + c4 * 4]) = v;
            }
        }
    } else {
        // edge tiles (~4% of blocks): scalar guarded staging, OOB -> 0
        for (int t = tid; t < SROWS * SCOLS; t += 256) {
            int r = t / SCOLS, c = t % SCOLS;
            int gr = row0 + r, gc = col0 + c;
            float v = (gr >= 0 && gr < IMG_H && gc >= 0 && gc < IMG_W)
                      ? img[(long)gr * IMG_W + gc] : 0.0f;
            tile[r * SSTRIDE + c] = v;
        }
    }
    __syncthreads();

    const int lane = tid & 63;
    const int wv   = tid >> 6;         // wave id 0..3 -> rows wv*4 .. wv*4+3
    const int w    = w0 + lane;

    #pragma unroll
    for (int k = 0; k < 4; ++k) {
        const int h   = h0 + wv * 4 + k;
        const int idx = h * IMG_W + w;

        const float fh = flow[idx];
        const float fw = flow[HW + idx];

        // exact reference grouping: (flow + mesh) + 1.0
        float Hu = (fh + (float)h) + 1.0f;
        float Wu = (fw + (float)w) + 1.0f;

        int hf = (int)floorf(Hu);
        int wf = (int)floorf(Wu);
        int hc = hf + 1;
        int wc = wf + 1;

        int hfc = min(max(hf, 0), IMG_H + 1);
        int hcc = min(max(hc, 0), IMG_H + 1);
        int wfc = min(max(wf, 0), IMG_W + 1);
        int wcc = min(max(wc, 0), IMG_W + 1);

        float dH = (float)hcc - Hu;   // weights from CLAMPED indices
        float dW = (float)wcc - Wu;

        // padded coord p -> img coord p-1 -> tile-relative
        int trf = (hfc - 1) - row0;
        int trc = (hcc - 1) - row0;
        int tcf = (wfc - 1) - col0;
        int tcc = (wcc - 1) - col0;

        float v00, v10, v01, v11;
        bool in_tile = ((unsigned)trf < SROWS) && ((unsigned)trc < SROWS) &&
                       ((unsigned)tcf < SCOLS) && ((unsigned)tcc < SCOLS);
        if (__builtin_expect(in_tile, 1)) {
            v00 = tile[trf * SSTRIDE + tcf];
            v10 = tile[trc * SSTRIDE + tcf];
            v01 = tile[trf * SSTRIDE + tcc];
            v11 = tile[trc * SSTRIDE + tcc];
        } else {
            // exact fallback for |flow| beyond margin (rare-to-never)
            bool hf_in = (hfc >= 1) && (hfc <= IMG_H);
            bool hc_in = (hcc >= 1) && (hcc <= IMG_H);
            bool wf_in = (wfc >= 1) && (wfc <= IMG_W);
            bool wc_in = (wcc >= 1) && (wcc <= IMG_W);
            long rowf = (long)(hfc - 1) * IMG_W;
            long rowc = (long)(hcc - 1) * IMG_W;
            v00 = (hf_in && wf_in) ? img[rowf + (wfc - 1)] : 0.0f;
            v10 = (hc_in && wf_in) ? img[rowc + (wfc - 1)] : 0.0f;
            v01 = (hf_in && wc_in) ? img[rowf + (wcc - 1)] : 0.0f;
            v11 = (hc_in && wc_in) ? img[rowc + (wcc - 1)] : 0.0f;
        }

        out[idx] = v00 * (dW * dH)
                 + v10 * (dW * (1.0f - dH))
                 + v01 * ((1.0f - dW) * dH)
                 + v11 * ((1.0f - dW) * (1.0f - dH));
    }
}

extern "C" void kernel_launch(void* const* d_in, const int* in_sizes, int n_in,
                              void* d_out, int out_size, void* d_ws, size_t ws_size,
                              hipStream_t stream) {
    const float* img  = (const float*)d_in[0];   // [1,1,4096,4096]
    const float* flow = (const float*)d_in[1];   // [1,2,4096,4096]
    float* out = (float*)d_out;                  // [1,1,4096,4096]

    dim3 grid(IMG_W / TILE_W, IMG_H / TILE_H);   // (64, 256)
    dim3 block(256);
    warp_bilinear_kernel<<<grid, block, 0, stream>>>(img, flow, out);
}

// Round 4
// 254.194 us; speedup vs baseline: 1.0633x; 1.0633x over previous
//
#include <hip/hip_runtime.h>

// Dense 2D spatial transformer (bilinear warp, dense flow), 4096x4096 f32.
//
// Round 4: MLP (memory-level-parallelism) kernel. R2/R3 post-mortem showed
// HBM 23-25%, VALU 26-31%, occupancy ~75% -- latency-bound, not throughput-
// bound. Fix: 4 pixels per thread (same column, rows 4 apart so every wave
// gather stays lane-contiguous), with ALL flow loads issued first, then ALL
// 16 tap gathers issued unconditionally (addresses clamped in-image; the
// zero-pad border is realized by zeroing the bilinear WEIGHTS, not by
// predicating loads -- keeps the loads branch-free and batchable).
// Flow loads / out stores are non-temporal: 192 MB of use-once stream
// traffic stays out of L2/L3 so the gathered image stays resident.
//
// Reference math replicated exactly (same as passing R1/R2/R3):
//   H_up=(flow_h+h)+1 ; W_up=(flow_w+w)+1 ; hf=floor, hc=hf+1, clamp to
//   [0,H+1] (padded dims); dH=(float)hc_clamped-H_up (clamp BEFORE weights);
//   out = v00*(dW*dH)+v10*(dW*(1-dH))+v01*((1-dW)*dH)+v11*((1-dW)*(1-dH)).

#define IMG_H 4096
#define IMG_W 4096

__global__ __launch_bounds__(256) void warp_bilinear_kernel(
    const float* __restrict__ img,   // [H, W]
    const float* __restrict__ flow,  // [2, H, W]
    float* __restrict__ out)         // [H, W]
{
    const int HW   = IMG_H * IMG_W;
    const int lane = threadIdx.x & 63;
    const int wv   = threadIdx.x >> 6;            // 0..3
    const int w    = blockIdx.x * 64 + lane;      // gridDim.x = 64
    const int h0   = blockIdx.y * 16 + wv;        // rows h0, h0+4, h0+8, h0+12

    int   idx[4];
    float fh[4], fw[4];

    #pragma unroll
    for (int k = 0; k < 4; ++k)
        idx[k] = (h0 + 4 * k) * IMG_W + w;

    // ---- phase 1: issue all 8 flow loads (independent, coalesced) ----
    #pragma unroll
    for (int k = 0; k < 4; ++k)
        fh[k] = __builtin_nontemporal_load(flow + idx[k]);
    #pragma unroll
    for (int k = 0; k < 4; ++k)
        fw[k] = __builtin_nontemporal_load(flow + HW + idx[k]);

    // ---- phase 2: all addresses + masked weights ----
    int   o00[4], o10[4], o01[4], o11[4];
    float w00[4], w10[4], w01[4], w11[4];

    #pragma unroll
    for (int k = 0; k < 4; ++k) {
        const int h = h0 + 4 * k;
        // exact reference grouping: (flow + mesh) + 1.0
        float Hu = (fh[k] + (float)h) + 1.0f;
        float Wu = (fw[k] + (float)w) + 1.0f;

        int hf = (int)floorf(Hu);
        int wf = (int)floorf(Wu);
        int hc = hf + 1;
        int wc = wf + 1;

        // clamp to padded range [0, H+1]; weights use CLAMPED indices
        int hfc = min(max(hf, 0), IMG_H + 1);
        int hcc = min(max(hc, 0), IMG_H + 1);
        int wfc = min(max(wf, 0), IMG_W + 1);
        int wcc = min(max(wc, 0), IMG_W + 1);

        float dH = (float)hcc - Hu;
        float dW = (float)wcc - Wu;

        // padded coord p -> img coord p-1; validity + clamped load address
        int rf = hfc - 1, rc = hcc - 1, cf = wfc - 1, cc = wcc - 1;
        bool rf_in = (unsigned)rf < IMG_H;
        bool rc_in = (unsigned)rc < IMG_H;
        bool cf_in = (unsigned)cf < IMG_W;
        bool cc_in = (unsigned)cc < IMG_W;
        int rf_cl = min(max(rf, 0), IMG_H - 1);
        int rc_cl = min(max(rc, 0), IMG_H - 1);
        int cf_cl = min(max(cf, 0), IMG_W - 1);
        int cc_cl = min(max(cc, 0), IMG_W - 1);

        o00[k] = (rf_cl << 12) + cf_cl;
        o10[k] = (rc_cl << 12) + cf_cl;
        o01[k] = (rf_cl << 12) + cc_cl;
        o11[k] = (rc_cl << 12) + cc_cl;

        float A = dW * dH;
        float B = dW * (1.0f - dH);
        float C = (1.0f - dW) * dH;
        float D = (1.0f - dW) * (1.0f - dH);
        // zero-pad border: out-of-image tap contributes 0 via its weight
        w00[k] = (rf_in && cf_in) ? A : 0.0f;
        w10[k] = (rc_in && cf_in) ? B : 0.0f;
        w01[k] = (rf_in && cc_in) ? C : 0.0f;
        w11[k] = (rc_in && cc_in) ? D : 0.0f;
    }

    // ---- phase 3: issue all 16 gathers (branch-free, batched) ----
    float v00[4], v10[4], v01[4], v11[4];
    #pragma unroll
    for (int k = 0; k < 4; ++k) {
        v00[k] = img[o00[k]];
        v10[k] = img[o10[k]];
        v01[k] = img[o01[k]];
        v11[k] = img[o11[k]];
    }

    // ---- phase 4: blend + store ----
    #pragma unroll
    for (int k = 0; k < 4; ++k) {
        float res = v00[k] * w00[k] + v10[k] * w10[k]
                  + v01[k] * w01[k] + v11[k] * w11[k];
        __builtin_nontemporal_store(res, out + idx[k]);
    }
}

extern "C" void kernel_launch(void* const* d_in, const int* in_sizes, int n_in,
                              void* d_out, int out_size, void* d_ws, size_t ws_size,
                              hipStream_t stream) {
    const float* img  = (const float*)d_in[0];   // [1,1,4096,4096]
    const float* flow = (const float*)d_in[1];   // [1,2,4096,4096]
    float* out = (float*)d_out;                  // [1,1,4096,4096]

    dim3 grid(IMG_W / 64, IMG_H / 16);           // (64, 256)
    dim3 block(256);
    warp_bilinear_kernel<<<grid, block, 0, stream>>>(img, flow, out);
}